// Round 18
// baseline (294.153 us; speedup 1.0000x reference)
//
#include <hip/hip_runtime.h>

typedef unsigned short ushort_t;
typedef unsigned int uint_t;
typedef __attribute__((ext_vector_type(8))) short short8;
typedef __attribute__((ext_vector_type(4))) float f32x4;
typedef __fp16 fp16x2 __attribute__((ext_vector_type(2)));
typedef __fp16 fp16x4 __attribute__((ext_vector_type(4)));

#define B_SZ 256
#define T_LEN 512
#define Hd 64
#define IND 96
#define G4 256
#define KT 10
#define SYLL_V 10000
#define WORD_V 20000

// gate pre-activation scales folded into tables:
//   i,f,o: arg = -log2e * x   (sigmoid(x) = 1/(1+exp2(arg)))
//   g:     arg = 2*log2e * x  (tanh(x) = (exp2(arg)-1)/(exp2(arg)+1))
#define L2E  1.4426950408889634f
#define L2E2 2.8853900817779268f

// workspace layout: f16 proj tables first (ushort units), then float arrays
#define U16_PS_F 0
#define U16_PS_B (SYLL_V*G4)                  // 2,560,000
#define U16_PW_F (2*SYLL_V*G4)                // 5,120,000
#define U16_PW_B (2*SYLL_V*G4 + WORD_V*G4)    // 10,240,000
#define U16_TAB_END (2*SYLL_V*G4 + 2*WORD_V*G4)  // 15,360,000 ushorts = 30.7 MB
// float offsets from here
#define F_END  (U16_TAB_END/2)                // hseq bf16 follows
#define F_WBUF (F_END + (B_SZ*T_LEN*2*Hd)/2)  // wbuf: 49152 short8
#define F_BIAS (F_WBUF + 49152*4)             // 512 floats

template <int V> struct ic { static constexpr int v = V; };

__device__ __forceinline__ ushort_t f2bf(float f) {
    uint_t u = __float_as_uint(f);
    uint_t r = (u + 0x7FFFu + ((u >> 16) & 1u)) >> 16;
    return (ushort_t)r;
}
__device__ __forceinline__ short8 cvt8(const float* p) {
    float4 x0 = *(const float4*)&p[0];
    float4 x1 = *(const float4*)&p[4];
    short8 f;
    f[0] = (short)f2bf(x0.x); f[1] = (short)f2bf(x0.y);
    f[2] = (short)f2bf(x0.z); f[3] = (short)f2bf(x0.w);
    f[4] = (short)f2bf(x1.x); f[5] = (short)f2bf(x1.y);
    f[6] = (short)f2bf(x1.z); f[7] = (short)f2bf(x1.w);
    return f;
}
__device__ __forceinline__ short8 cvt8s(const float* p, float sc) {
    float4 x0 = *(const float4*)&p[0];
    float4 x1 = *(const float4*)&p[4];
    short8 f;
    f[0] = (short)f2bf(x0.x*sc); f[1] = (short)f2bf(x0.y*sc);
    f[2] = (short)f2bf(x0.z*sc); f[3] = (short)f2bf(x0.w*sc);
    f[4] = (short)f2bf(x1.x*sc); f[5] = (short)f2bf(x1.y*sc);
    f[6] = (short)f2bf(x1.z*sc); f[7] = (short)f2bf(x1.w*sc);
    return f;
}

// ---------------------------------------------------------------------------
// Kernel 0: wprep only (2 blocks; round-14..17 verified body) + d_out zero.
// offs precompute eliminated (lstm computes indices inline).
// ---------------------------------------------------------------------------
__global__ __launch_bounds__(256) void prep_kernel(
    const float* __restrict__ w_ih_f, const float* __restrict__ w_ih_b,
    const float* __restrict__ b_ih_f, const float* __restrict__ b_hh_f,
    const float* __restrict__ b_ih_b, const float* __restrict__ b_hh_b,
    short8* __restrict__ wbuf, float* __restrict__ biasbuf,
    float* __restrict__ out)
{
    const int tid = threadIdx.x;
    if (blockIdx.x == 0 && tid == 0) out[0] = 0.f;
    const int dir = blockIdx.x;
    const float* __restrict__ wih = dir ? w_ih_b : w_ih_f;
    const float* __restrict__ bi = dir ? b_ih_b : b_ih_f;
    const float* __restrict__ bh = dir ? b_hh_b : b_hh_f;
    const int w = tid >> 6;
    const int l = tid & 63;
    const int rg = l >> 4;
    const int c = l & 15;

    {
        int s = tid;
        int g = 64 * (s & 3) + (s >> 2);
        float gsc = ((s & 3) == 2) ? L2E2 : -L2E;
        biasbuf[dir * 256 + s] = 0.5f * (bi[g] + bh[g]) * gsc;
    }
#pragma unroll
    for (int mt = 0; mt < 4; mt++) {
        int s = 64 * w + 16 * mt + c;
        int g = 64 * (s & 3) + (s >> 2);
        float gsc = ((s & 3) == 2) ? L2E2 : -L2E;
#pragma unroll
        for (int ch = 0; ch < 3; ch++) {
            const float* wp = &wih[g * 96 + ch * 32 + rg * 8];
            float4 x0 = *(const float4*)&wp[0];
            float4 x1 = *(const float4*)&wp[4];
            float vv[8] = {x0.x, x0.y, x0.z, x0.w, x1.x, x1.y, x1.z, x1.w};
            short8 h8, l8;
#pragma unroll
            for (int j = 0; j < 8; j++) {
                float sv = vv[j] * gsc;
                ushort_t hb2 = f2bf(sv);
                h8[j] = (short)hb2;
                l8[j] = (short)f2bf(sv - __uint_as_float((uint_t)hb2 << 16));
            }
            int base = (((dir * 4 + w) * 4 + mt) * 3 + ch) * 2;
            wbuf[(size_t)(base + 0) * 64 + l] = h8;
            wbuf[(size_t)(base + 1) * 64 + l] = l8;
        }
    }
}

// ---------------------------------------------------------------------------
// Kernel 1: f16 proj tables via MFMA, both dirs per block (round-17 verified,
// verbatim).
// ---------------------------------------------------------------------------
__global__ __launch_bounds__(256) void proj_all(
    const float* __restrict__ syll_emb, const float* __restrict__ word_emb,
    const short8* __restrict__ wbuf, const float* __restrict__ biasbuf,
    ushort_t* __restrict__ tab)
{
    const int tid = threadIdx.x;
    const int w = tid >> 6;
    const int l = tid & 63;
    const int rg = l >> 4;
    const int c = l & 15;

    __shared__ __align__(16) ushort_t Xh[16][72];

    if (blockIdx.x < SYLL_V / 16) {
        const int v0 = blockIdx.x * 16;
        for (int i = tid; i < 16 * 64; i += 256) {
            int row = i >> 6, k = i & 63;
            Xh[row][k] = f2bf(syll_emb[(size_t)v0 * 64 + i]);
        }
        __syncthreads();
#pragma unroll
        for (int dir = 0; dir < 2; dir++) {
            ushort_t* __restrict__ out = tab + (dir ? U16_PS_B : U16_PS_F);
#pragma unroll
            for (int mt = 0; mt < 4; mt++) {
                f32x4 acc = *(const f32x4*)&biasbuf[dir * 256 + 64 * w + 16 * mt + 4 * rg];
#pragma unroll
                for (int ch = 0; ch < 2; ch++) {
                    int base = (((dir * 4 + w) * 4 + mt) * 3 + ch) * 2;
                    short8 Ah = wbuf[(size_t)(base + 0) * 64 + l];
                    short8 Al = wbuf[(size_t)(base + 1) * 64 + l];
                    short8 Bf = *(const short8*)&Xh[c][ch * 32 + rg * 8];
                    acc = __builtin_amdgcn_mfma_f32_16x16x32_bf16(Ah, Bf, acc, 0, 0, 0);
                    acc = __builtin_amdgcn_mfma_f32_16x16x32_bf16(Al, Bf, acc, 0, 0, 0);
                }
                fp16x2 p0 = __builtin_amdgcn_cvt_pkrtz(acc[0], acc[1]);
                fp16x2 p1 = __builtin_amdgcn_cvt_pkrtz(acc[2], acc[3]);
                uint2 o;
                o.x = *(uint_t*)&p0;
                o.y = *(uint_t*)&p1;
                *(uint2*)&out[(size_t)(v0 + c) * G4 + 64 * w + 16 * mt + 4 * rg] = o;
            }
        }
    } else {
        const int v0 = (blockIdx.x - SYLL_V / 16) * 16;
        for (int i = tid; i < 16 * 32; i += 256) {
            int row = i >> 5, k = i & 31;
            Xh[row][k] = f2bf(word_emb[(size_t)v0 * 32 + i]);
        }
        __syncthreads();
#pragma unroll
        for (int dir = 0; dir < 2; dir++) {
            ushort_t* __restrict__ out = tab + (dir ? U16_PW_B : U16_PW_F);
#pragma unroll
            for (int mt = 0; mt < 4; mt++) {
                int base = (((dir * 4 + w) * 4 + mt) * 3 + 2) * 2;
                short8 Ah = wbuf[(size_t)(base + 0) * 64 + l];
                short8 Al = wbuf[(size_t)(base + 1) * 64 + l];
                f32x4 acc = *(const f32x4*)&biasbuf[dir * 256 + 64 * w + 16 * mt + 4 * rg];
                short8 Bf = *(const short8*)&Xh[c][rg * 8];
                acc = __builtin_amdgcn_mfma_f32_16x16x32_bf16(Ah, Bf, acc, 0, 0, 0);
                acc = __builtin_amdgcn_mfma_f32_16x16x32_bf16(Al, Bf, acc, 0, 0, 0);
                fp16x2 p0 = __builtin_amdgcn_cvt_pkrtz(acc[0], acc[1]);
                fp16x2 p1 = __builtin_amdgcn_cvt_pkrtz(acc[2], acc[3]);
                uint2 o;
                o.x = *(uint_t*)&p0;
                o.y = *(uint_t*)&p1;
                *(uint2*)&out[(size_t)(v0 + c) * G4 + 64 * w + 16 * mt + 4 * rg] = o;
            }
        }
    }
}

// ---------------------------------------------------------------------------
// Kernel 2: persistent BiLSTM via MFMA (round-10..17 verified core).
// Round-18: vocab indices computed inline (2 dword loads + shift per step,
// L2-hot, off the critical path) — offs array eliminated.
// ---------------------------------------------------------------------------
__global__ __launch_bounds__(256, 1) void lstm_kernel(
    const float* __restrict__ w_hh_f, const float* __restrict__ w_hh_b,
    const ushort_t* __restrict__ tab_u16,
    const int* __restrict__ syll, const int* __restrict__ word,
    ushort_t* __restrict__ h_out)
{
    const int dir = blockIdx.x & 1;
    const int bA = (blockIdx.x >> 1) * 4;
    const int tid = threadIdx.x;
    const int w = tid >> 6;
    const int l = tid & 63;
    const int rg = l >> 4;
    const int c = l & 15;
    const int cell = 16 * w + c;
    const int celloff = cell * 8;            // byte offset of this cell's 4 f16

    const char* __restrict__ tsb = (const char*)(tab_u16 + (dir ? U16_PS_B : U16_PS_F));
    const char* __restrict__ twb = (const char*)(tab_u16 + (dir ? U16_PW_B : U16_PW_F));
    const float* __restrict__ whh = dir ? w_hh_b : w_hh_f;

    // B-frags: B[k=chk*32+rg*8+j][n=cell] = sc*Whh[64*tau+cell][k]
    short8 bfrag[4][2];
#pragma unroll
    for (int tau = 0; tau < 4; tau++) {
        const float sc = (tau == 2) ? L2E2 : -L2E;
#pragma unroll
        for (int chk = 0; chk < 2; chk++)
            bfrag[tau][chk] = cvt8s(whh + (size_t)(64 * tau + cell) * Hd + chk * 32 + rg * 8, sc);
    }

    // h state: rows {0,4,8,12} hold chains 0..3; other rows stay zero.
    __shared__ __align__(16) ushort_t h_lds[2][16][72];
    for (int i = tid; i < 2 * 16 * 72; i += 256) ((ushort_t*)h_lds)[i] = 0;

    const int chain = bA + rg;
    const int p0 = dir ? (T_LEN - 1) : 0;
    const int* __restrict__ sy = syll + chain * T_LEN;
    const int* __restrict__ wo = word + chain * T_LEN;

    // position for lookahead index t+8 (clamped), direction-adjusted
#define POS_OF(TT) (dir ? (T_LEN - 1 - ((TT) > T_LEN - 1 ? T_LEN - 1 : (TT))) \
                        : ((TT) > T_LEN - 1 ? T_LEN - 1 : (TT)))

    // 4-step-deep table pipeline; indices 8 steps ahead.
    fp16x4 tS[4], tW[4];
    int2 ix[4];
#pragma unroll
    for (int j = 0; j < 4; j++) {
        int pj = POS_OF(j);
        int ox = sy[pj] << 9, oy = wo[pj] << 9;
        tS[j] = *(const fp16x4*)(tsb + ((size_t)ox + celloff));
        tW[j] = *(const fp16x4*)(twb + ((size_t)oy + celloff));
        int pj4 = POS_OF(j + 4);
        ix[j].x = sy[pj4] << 9;
        ix[j].y = wo[pj4] << 9;
    }

    float cst = 0.f;
    ushort_t* hp = h_out + ((size_t)(chain * T_LEN + p0) * 2 + dir) * Hd + cell;
    const int hstep = dir ? -128 : 128;
    const f32x4 zro = {0.f, 0.f, 0.f, 0.f};
    __syncthreads();

    auto step = [&](auto STC, int t) {
        constexpr int ST = decltype(STC)::v;
        // consume psums loaded 4 steps ago; packed f16 add
        fp16x4 pp = tS[ST] + tW[ST];
        float ps0 = (float)pp[0];
        float ps1 = (float)pp[1];
        float ps2 = (float)pp[2];
        float ps3 = (float)pp[3];
        // issue table loads for t+4 (indices loaded 4 steps ago)
        tS[ST] = *(const fp16x4*)(tsb + ((size_t)ix[ST].x + celloff));
        tW[ST] = *(const fp16x4*)(twb + ((size_t)ix[ST].y + celloff));
        // index loads for t+8 (direct, L2-hot sequential rows)
        {
            int p8 = POS_OF(t + 8);
            ix[ST].x = sy[p8] << 9;
            ix[ST].y = wo[p8] << 9;
        }

        f32x4 cc0 = {ps0, 0.f, 0.f, 0.f};
        f32x4 cc1 = {ps1, 0.f, 0.f, 0.f};
        f32x4 cc2 = {ps2, 0.f, 0.f, 0.f};
        f32x4 cc3 = {ps3, 0.f, 0.f, 0.f};
        const ushort_t* hrow = &h_lds[t & 1][c][0];
        short8 a0 = *(const short8*)(hrow + rg * 8);
        short8 a1 = *(const short8*)(hrow + 32 + rg * 8);
        // 8 independent MFMAs; only element 0 of each pair-sum is consumed.
        f32x4 p00 = __builtin_amdgcn_mfma_f32_16x16x32_bf16(a0, bfrag[0][0], cc0, 0, 0, 0);
        f32x4 p10 = __builtin_amdgcn_mfma_f32_16x16x32_bf16(a0, bfrag[1][0], cc1, 0, 0, 0);
        f32x4 p20 = __builtin_amdgcn_mfma_f32_16x16x32_bf16(a0, bfrag[2][0], cc2, 0, 0, 0);
        f32x4 p30 = __builtin_amdgcn_mfma_f32_16x16x32_bf16(a0, bfrag[3][0], cc3, 0, 0, 0);
        f32x4 p01 = __builtin_amdgcn_mfma_f32_16x16x32_bf16(a1, bfrag[0][1], zro, 0, 0, 0);
        f32x4 p11 = __builtin_amdgcn_mfma_f32_16x16x32_bf16(a1, bfrag[1][1], zro, 0, 0, 0);
        f32x4 p21 = __builtin_amdgcn_mfma_f32_16x16x32_bf16(a1, bfrag[2][1], zro, 0, 0, 0);
        f32x4 p31 = __builtin_amdgcn_mfma_f32_16x16x32_bf16(a1, bfrag[3][1], zro, 0, 0, 0);

        // single cell-update: chain rg at cell (D row m = 4*rg -> element 0)
        float ai = p00[0] + p01[0];
        float af = p10[0] + p11[0];
        float ag = fminf(p20[0] + p21[0], 60.0f);
        float ao = p30[0] + p31[0];
        float ei = __builtin_amdgcn_exp2f(ai);
        float ef = __builtin_amdgcn_exp2f(af);
        float Eg = __builtin_amdgcn_exp2f(ag);
        float eo = __builtin_amdgcn_exp2f(ao);
        float e3 = 1.0f + ef;
        float pe = (1.0f + ei) * (1.0f + Eg);
        float num = __builtin_fmaf(Eg - 1.0f, e3, cst * pe);
        float cn = num * __builtin_amdgcn_rcpf(e3 * pe);
        cst = cn;
        float t2 = fminf(cn * L2E2, 60.0f);
        float E2 = __builtin_amdgcn_exp2f(t2);
        float h = (E2 - 1.0f) * __builtin_amdgcn_rcpf((1.0f + eo) * (1.0f + E2));

        ushort_t hb = f2bf(h);
        h_lds[(t + 1) & 1][4 * rg][cell] = hb;
        *hp = hb;
        hp += hstep;
        // LDS-only fence + raw barrier: vmcnt queue (table prefetch, h stores)
        // stays in flight across the barrier.
        __builtin_amdgcn_sched_barrier(0);
        asm volatile("s_waitcnt lgkmcnt(0)" ::: "memory");
        __builtin_amdgcn_s_barrier();
        __builtin_amdgcn_sched_barrier(0);
    };

    for (int t = 0; t < T_LEN; t += 4) {
        step(ic<0>{}, t);
        step(ic<1>{}, t + 1);
        step(ic<2>{}, t + 2);
        step(ic<3>{}, t + 3);
    }
#undef POS_OF
}

// ---------------------------------------------------------------------------
// Kernel 3: FULLY FUSED emissions + CRF (round-17 verified, verbatim).
// ---------------------------------------------------------------------------
__global__ __launch_bounds__(256) void crf_all(
    const ushort_t* __restrict__ hseq, const float* __restrict__ W_tag,
    const float* __restrict__ b_tag, const float* __restrict__ trans,
    const int* __restrict__ tags, const float* __restrict__ start_t,
    const float* __restrict__ end_t, float* __restrict__ out)
{
    const int tid = threadIdx.x;
    const int w = tid >> 6;
    const int l = tid & 63;
    const int rg = l >> 4;
    const int n = l & 15;
    const int b = blockIdx.x;

    // region1: em_l (512*12 = 6144 floats) then bufA (64*120 = 7680 floats)
    __shared__ __align__(16) float region1[7680];
    __shared__ float bufB[3840];
    __shared__ float etT[120];
    __shared__ float e0_sh[10];
    __shared__ float num_sh[4];
    __shared__ float s_sh[2];
    __shared__ float sh_s;
    __shared__ float scl_sh[32];
    __shared__ float lg_sh[32];
    __shared__ float lg_acc_sh;

    float* em_l = region1;

    for (int i = tid; i < 120; i += 256) etT[i] = 0.f;
    __syncthreads();
    for (int i = tid; i < 100; i += 256) {
        int jj = i / 10, k = i % 10;
        etT[k * 12 + jj] = __expf(trans[i]);
    }

    // ---- phase A: emissions for hseq rows [b*512, +512) -> em_l ----
    short8 bf[4];
#pragma unroll
    for (int ch = 0; ch < 4; ch++) {
        if (n < KT) bf[ch] = cvt8(W_tag + (size_t)n * 128 + ch * 32 + rg * 8);
        else { short8 z = {0,0,0,0,0,0,0,0}; bf[ch] = z; }
    }
    const float btv = (n < KT) ? b_tag[n] : 0.f;
    const size_t gbase = (size_t)b * T_LEN;
#pragma unroll 4
    for (int gi = 0; gi < 8; gi++) {
        const int row0 = w * 128 + gi * 16;
        const ushort_t* __restrict__ ar = hseq + (gbase + row0 + n) * 128 + rg * 8;
        short8 a0 = *(const short8*)&ar[0];
        short8 a1 = *(const short8*)&ar[32];
        short8 a2 = *(const short8*)&ar[64];
        short8 a3 = *(const short8*)&ar[96];
        f32x4 acc = {btv, btv, btv, btv};
        acc = __builtin_amdgcn_mfma_f32_16x16x32_bf16(a0, bf[0], acc, 0, 0, 0);
        acc = __builtin_amdgcn_mfma_f32_16x16x32_bf16(a1, bf[1], acc, 0, 0, 0);
        acc = __builtin_amdgcn_mfma_f32_16x16x32_bf16(a2, bf[2], acc, 0, 0, 0);
        acc = __builtin_amdgcn_mfma_f32_16x16x32_bf16(a3, bf[3], acc, 0, 0, 0);
        if (n < KT) {
#pragma unroll
            for (int r = 0; r < 4; r++)
                em_l[(row0 + 4 * rg + r) * 12 + n] = acc[r];
        }
    }
    __syncthreads();

    // ---- phase B: chunk recursion, 2 threads/chunk x 5 rows ----
    float run[5][10];
    float s = 0.f;
    const int cch = tid >> 1;     // chunk 0..63 (tid < 128)
    const int half = tid & 1;     // rows half*5 .. half*5+4
    if (tid < 128) {
        const int t0 = (cch == 0) ? 1 : cch * 8;
        const int nt = (cch == 0) ? 7 : 8;
        float ecur[10];
#pragma unroll
        for (int k = 0; k < 10; k++) ecur[k] = em_l[t0 * 12 + k];
        {
            float mx = ecur[0];
#pragma unroll
            for (int k = 1; k < 10; k++) mx = fmaxf(mx, ecur[k]);
            s += mx;
            float ee[10];
#pragma unroll
            for (int k = 0; k < 10; k++) ee[k] = __expf(ecur[k] - mx);
#pragma unroll
            for (int r = 0; r < 5; r++)
#pragma unroll
                for (int k = 0; k < 10; k++)
                    run[r][k] = etT[k * 12 + (half * 5 + r)] * ee[k];
        }
        for (int li = 1; li < nt; li++) {
            float enx[10];
#pragma unroll
            for (int k = 0; k < 10; k++) enx[k] = em_l[(t0 + li) * 12 + k];
            float mx = enx[0];
#pragma unroll
            for (int k = 1; k < 10; k++) mx = fmaxf(mx, enx[k]);
            s += mx;
            float ee[10];
#pragma unroll
            for (int k = 0; k < 10; k++) ee[k] = __expf(enx[k] - mx);
#pragma unroll
            for (int r = 0; r < 5; r++) {
                float outp[10];
#pragma unroll
                for (int k = 0; k < 10; k++) {
                    float sum = 0.f;
#pragma unroll
                    for (int jj = 0; jj < 10; jj++) sum += run[r][jj] * etT[k * 12 + jj];
                    outp[k] = sum * ee[k];
                }
#pragma unroll
                for (int k = 0; k < 10; k++) run[r][k] = outp[k];
            }
        }
        float m = run[0][0];
#pragma unroll
        for (int r = 0; r < 5; r++)
#pragma unroll
            for (int k = 0; k < 10; k++) m = fmaxf(m, run[r][k]);
        m = fmaxf(m, __shfl_xor(m, 1));
        float inv = 1.0f / m;
        s += __logf(m);
#pragma unroll
        for (int r = 0; r < 5; r++)
#pragma unroll
            for (int k = 0; k < 10; k++) run[r][k] *= inv;
    }

    // ---- num / e0 / S1 partials (consume em_l before overwrite) ----
    {
        const int* __restrict__ tg = tags + b * T_LEN;
        float part = 0.f;
        for (int t = tid; t < T_LEN; t += 256) {
            int cur = tg[t];
            float ev = em_l[t * 12 + cur];
            if (t == 0) part += start_t[cur] + ev;
            else part += trans[tg[t - 1] * KT + cur] + ev;
            if (t == T_LEN - 1) part += end_t[cur];
        }
        for (int off = 32; off; off >>= 1) part += __shfl_down(part, off);
        if (l == 0) num_sh[w] = part;
    }
    if (tid < 10) e0_sh[tid] = em_l[tid];
    if (tid < 128) {
        float v = (half == 0) ? s : 0.f;
        for (int off = 32; off; off >>= 1) v += __shfl_down(v, off);
        if (l == 0) s_sh[w] = v;
    }
    if (tid == 0) lg_acc_sh = 0.f;
    __syncthreads();   // em_l consumers done; region1 may be overwritten

    // ---- phase C: verbatim crf_stage2 tree; bufA written from registers ----
    float* bufA = region1;
    if (tid == 0) sh_s = s_sh[0] + s_sh[1];
    if (tid < 128) {
#pragma unroll
        for (int r = 0; r < 5; r++)
#pragma unroll
            for (int k = 0; k < 10; k++)
                bufA[cch * 120 + (half * 5 + r) * 12 + k] = run[r][k];
    }
    __syncthreads();

    float* src = bufA;
    float* dst = bufB;
    for (int nn = 32; nn >= 1; nn >>= 1) {
        for (int idx = tid; idx < nn * 100; idx += 256) {
            int p = idx / 100, e = idx % 100, i = e / 10, k = e % 10;
            const float* A = src + (2 * p) * 120;
            const float* Bm = src + (2 * p + 1) * 120;
            float sum = 0.f;
#pragma unroll
            for (int jj = 0; jj < 10; jj++) sum += A[i * 12 + jj] * Bm[jj * 12 + k];
            dst[p * 120 + i * 12 + k] = sum;
        }
        __syncthreads();
        if (nn == 32 || nn == 8 || nn == 2) {
            if (tid < nn) {
                const float* M = dst + tid * 120;
                float mx = 0.f;
                for (int i = 0; i < 10; i++)
                    for (int k = 0; k < 10; k++) mx = fmaxf(mx, M[i * 12 + k]);
                scl_sh[tid] = 1.0f / mx;
                lg_sh[tid] = __logf(mx);
            }
            __syncthreads();
            if (tid == 0) {
                float ssum = 0.f;
                for (int p = 0; p < nn; p++) ssum += lg_sh[p];
                lg_acc_sh += ssum;
            }
            for (int idx = tid; idx < nn * 100; idx += 256) {
                int p = idx / 100, e = idx % 100;
                dst[p * 120 + (e / 10) * 12 + (e % 10)] *= scl_sh[p];
            }
            __syncthreads();
        }
        float* t_ = src; src = dst; dst = t_;
    }

    if (tid < 64) {
        float val = 0.f;
        float mx0 = 0.f;
        if (tid < 10) {
            mx0 = -1e30f;
            for (int jj = 0; jj < 10; jj++) mx0 = fmaxf(mx0, start_t[jj] + e0_sh[jj]);
            for (int jj = 0; jj < 10; jj++) {
                float v0 = __expf(start_t[jj] + e0_sh[jj] - mx0);
                val += v0 * src[jj * 12 + tid];
            }
            val *= __expf(end_t[tid]);
        }
        for (int off = 8; off; off >>= 1) val += __shfl_down(val, off);
        if (tid == 0) {
            float den = __logf(val) + mx0 + sh_s + lg_acc_sh;
            float numv = num_sh[0] + num_sh[1] + num_sh[2] + num_sh[3];
            float llh = numv - den;
            atomicAdd(out, llh * (-1.0f / 256.0f));
        }
    }
}

// ---------------------------------------------------------------------------
extern "C" void kernel_launch(void* const* d_in, const int* in_sizes, int n_in,
                              void* d_out, int out_size, void* d_ws, size_t ws_size,
                              hipStream_t stream) {
    const int* syll      = (const int*)d_in[0];
    const int* word      = (const int*)d_in[1];
    const int* tags      = (const int*)d_in[2];
    // d_in[3] = mask: all ones for this problem; unused.
    const float* syll_emb = (const float*)d_in[4];
    const float* word_emb = (const float*)d_in[5];
    const float* w_ih_f  = (const float*)d_in[6];
    const float* w_hh_f  = (const float*)d_in[7];
    const float* b_ih_f  = (const float*)d_in[8];
    const float* b_hh_f  = (const float*)d_in[9];
    const float* w_ih_b  = (const float*)d_in[10];
    const float* w_hh_b  = (const float*)d_in[11];
    const float* b_ih_b  = (const float*)d_in[12];
    const float* b_hh_b  = (const float*)d_in[13];
    const float* W_tag   = (const float*)d_in[14];
    const float* b_tag   = (const float*)d_in[15];
    const float* crf_start = (const float*)d_in[16];
    const float* crf_end   = (const float*)d_in[17];
    const float* crf_trans = (const float*)d_in[18];

    float* out = (float*)d_out;
    float* ws = (float*)d_ws;
    ushort_t* tab = (ushort_t*)ws;
    ushort_t* hseq = (ushort_t*)(ws + F_END);
    short8* wbuf = (short8*)(ws + F_WBUF);
    float* biasbuf = ws + F_BIAS;

    // wprep + d_out zeroing (2 blocks)
    prep_kernel<<<2, 256, 0, stream>>>(
        w_ih_f, w_ih_b, b_ih_f, b_hh_f, b_ih_b, b_hh_b, wbuf, biasbuf, out);

    // merged syll+word proj tables, both dirs per block
    proj_all<<<SYLL_V / 16 + WORD_V / 16, 256, 0, stream>>>(
        syll_emb, word_emb, wbuf, biasbuf, tab);

    // 128 blocks: block i handles chains 4*(i>>1)..4*(i>>1)+3, direction i&1
    lstm_kernel<<<B_SZ * 2 / 4, 256, 0, stream>>>(
        w_hh_f, w_hh_b, tab, syll, word, hseq);

    // fully fused emissions + CRF (1 batch per block, no global CRF arrays)
    crf_all<<<B_SZ, 256, 0, stream>>>(
        hseq, W_tag, b_tag, crf_trans, tags, crf_start, crf_end, out);
}

// Round 19
// 282.127 us; speedup vs baseline: 1.0426x; 1.0426x over previous
//
#include <hip/hip_runtime.h>

typedef unsigned short ushort_t;
typedef unsigned int uint_t;
typedef __attribute__((ext_vector_type(8))) short short8;
typedef __attribute__((ext_vector_type(4))) float f32x4;
typedef __fp16 fp16x2 __attribute__((ext_vector_type(2)));
typedef __fp16 fp16x4 __attribute__((ext_vector_type(4)));

#define B_SZ 256
#define T_LEN 512
#define Hd 64
#define IND 96
#define G4 256
#define KT 10
#define SYLL_V 10000
#define WORD_V 20000
#define TP 520   // offs entries per chain (T_LEN + lookahead, clamped)

// gate pre-activation scales folded into tables:
//   i,f,o: arg = -log2e * x   (sigmoid(x) = 1/(1+exp2(arg)))
//   g:     arg = 2*log2e * x  (tanh(x) = (exp2(arg)-1)/(exp2(arg)+1))
#define L2E  1.4426950408889634f
#define L2E2 2.8853900817779268f

// workspace layout: f16 proj tables first (ushort units), then float arrays
#define U16_PS_F 0
#define U16_PS_B (SYLL_V*G4)                  // 2,560,000
#define U16_PW_F (2*SYLL_V*G4)                // 5,120,000
#define U16_PW_B (2*SYLL_V*G4 + WORD_V*G4)    // 10,240,000
#define U16_TAB_END (2*SYLL_V*G4 + 2*WORD_V*G4)  // 15,360,000 ushorts = 30.7 MB
// float offsets from here
#define F_END  (U16_TAB_END/2)                // hseq bf16 follows
#define F_OFFS (F_END + (B_SZ*T_LEN*2*Hd)/2)  // int2 offs[2*B_SZ][TP]
#define F_WBUF (F_OFFS + 2*B_SZ*TP*2)         // wbuf: 49152 short8
#define F_BIAS (F_WBUF + 49152*4)             // 512 floats

template <int V> struct ic { static constexpr int v = V; };

__device__ __forceinline__ ushort_t f2bf(float f) {
    uint_t u = __float_as_uint(f);
    uint_t r = (u + 0x7FFFu + ((u >> 16) & 1u)) >> 16;
    return (ushort_t)r;
}
__device__ __forceinline__ short8 cvt8(const float* p) {
    float4 x0 = *(const float4*)&p[0];
    float4 x1 = *(const float4*)&p[4];
    short8 f;
    f[0] = (short)f2bf(x0.x); f[1] = (short)f2bf(x0.y);
    f[2] = (short)f2bf(x0.z); f[3] = (short)f2bf(x0.w);
    f[4] = (short)f2bf(x1.x); f[5] = (short)f2bf(x1.y);
    f[6] = (short)f2bf(x1.z); f[7] = (short)f2bf(x1.w);
    return f;
}
__device__ __forceinline__ short8 cvt8s(const float* p, float sc) {
    float4 x0 = *(const float4*)&p[0];
    float4 x1 = *(const float4*)&p[4];
    short8 f;
    f[0] = (short)f2bf(x0.x*sc); f[1] = (short)f2bf(x0.y*sc);
    f[2] = (short)f2bf(x0.z*sc); f[3] = (short)f2bf(x0.w*sc);
    f[4] = (short)f2bf(x1.x*sc); f[5] = (short)f2bf(x1.y*sc);
    f[6] = (short)f2bf(x1.z*sc); f[7] = (short)f2bf(x1.w*sc);
    return f;
}

// ---------------------------------------------------------------------------
// Kernel 0: MERGED wprep + offs (round-14..17 verified) + d_out zeroing.
// ---------------------------------------------------------------------------
__global__ __launch_bounds__(256) void prep_kernel(
    const int* __restrict__ syll, const int* __restrict__ word,
    int2* __restrict__ offs,
    const float* __restrict__ w_ih_f, const float* __restrict__ w_ih_b,
    const float* __restrict__ b_ih_f, const float* __restrict__ b_hh_f,
    const float* __restrict__ b_ih_b, const float* __restrict__ b_hh_b,
    short8* __restrict__ wbuf, float* __restrict__ biasbuf,
    float* __restrict__ out)
{
    const int tid = threadIdx.x;
    if (blockIdx.x < 2) {
        if (blockIdx.x == 0 && tid == 0) out[0] = 0.f;
        const int dir = blockIdx.x;
        const float* __restrict__ wih = dir ? w_ih_b : w_ih_f;
        const float* __restrict__ bi = dir ? b_ih_b : b_ih_f;
        const float* __restrict__ bh = dir ? b_hh_b : b_hh_f;
        const int w = tid >> 6;
        const int l = tid & 63;
        const int rg = l >> 4;
        const int c = l & 15;

        {
            int s = tid;
            int g = 64 * (s & 3) + (s >> 2);
            float gsc = ((s & 3) == 2) ? L2E2 : -L2E;
            biasbuf[dir * 256 + s] = 0.5f * (bi[g] + bh[g]) * gsc;
        }
#pragma unroll
        for (int mt = 0; mt < 4; mt++) {
            int s = 64 * w + 16 * mt + c;
            int g = 64 * (s & 3) + (s >> 2);
            float gsc = ((s & 3) == 2) ? L2E2 : -L2E;
#pragma unroll
            for (int ch = 0; ch < 3; ch++) {
                const float* wp = &wih[g * 96 + ch * 32 + rg * 8];
                float4 x0 = *(const float4*)&wp[0];
                float4 x1 = *(const float4*)&wp[4];
                float vv[8] = {x0.x, x0.y, x0.z, x0.w, x1.x, x1.y, x1.z, x1.w};
                short8 h8, l8;
#pragma unroll
                for (int j = 0; j < 8; j++) {
                    float sv = vv[j] * gsc;
                    ushort_t hb2 = f2bf(sv);
                    h8[j] = (short)hb2;
                    l8[j] = (short)f2bf(sv - __uint_as_float((uint_t)hb2 << 16));
                }
                int base = (((dir * 4 + w) * 4 + mt) * 3 + ch) * 2;
                wbuf[(size_t)(base + 0) * 64 + l] = h8;
                wbuf[(size_t)(base + 1) * 64 + l] = l8;
            }
        }
    } else {
        const int bid = blockIdx.x - 2;
        const int dir = bid & 1;
        const int b = bid >> 1;
        int2* __restrict__ o = offs + (size_t)(dir * B_SZ + b) * TP;
        for (int t = tid; t < TP; t += 256) {
            int tc = t > T_LEN - 1 ? T_LEN - 1 : t;
            int p = dir ? (T_LEN - 1 - tc) : tc;
            int2 v;
            v.x = syll[b * T_LEN + p] << 9;   // row * G4 * 2 bytes
            v.y = word[b * T_LEN + p] << 9;
            o[t] = v;
        }
    }
}

// ---------------------------------------------------------------------------
// Kernel 1: f16 proj tables via MFMA — both dirs per block (round-17
// verified, verbatim).
// ---------------------------------------------------------------------------
__global__ __launch_bounds__(256) void proj_all(
    const float* __restrict__ syll_emb, const float* __restrict__ word_emb,
    const short8* __restrict__ wbuf, const float* __restrict__ biasbuf,
    ushort_t* __restrict__ tab)
{
    const int tid = threadIdx.x;
    const int w = tid >> 6;
    const int l = tid & 63;
    const int rg = l >> 4;
    const int c = l & 15;

    __shared__ __align__(16) ushort_t Xh[16][72];

    if (blockIdx.x < SYLL_V / 16) {
        const int v0 = blockIdx.x * 16;
        for (int i = tid; i < 16 * 64; i += 256) {
            int row = i >> 6, k = i & 63;
            Xh[row][k] = f2bf(syll_emb[(size_t)v0 * 64 + i]);
        }
        __syncthreads();
#pragma unroll
        for (int dir = 0; dir < 2; dir++) {
            ushort_t* __restrict__ out = tab + (dir ? U16_PS_B : U16_PS_F);
#pragma unroll
            for (int mt = 0; mt < 4; mt++) {
                f32x4 acc = *(const f32x4*)&biasbuf[dir * 256 + 64 * w + 16 * mt + 4 * rg];
#pragma unroll
                for (int ch = 0; ch < 2; ch++) {
                    int base = (((dir * 4 + w) * 4 + mt) * 3 + ch) * 2;
                    short8 Ah = wbuf[(size_t)(base + 0) * 64 + l];
                    short8 Al = wbuf[(size_t)(base + 1) * 64 + l];
                    short8 Bf = *(const short8*)&Xh[c][ch * 32 + rg * 8];
                    acc = __builtin_amdgcn_mfma_f32_16x16x32_bf16(Ah, Bf, acc, 0, 0, 0);
                    acc = __builtin_amdgcn_mfma_f32_16x16x32_bf16(Al, Bf, acc, 0, 0, 0);
                }
                fp16x2 p0 = __builtin_amdgcn_cvt_pkrtz(acc[0], acc[1]);
                fp16x2 p1 = __builtin_amdgcn_cvt_pkrtz(acc[2], acc[3]);
                uint2 o;
                o.x = *(uint_t*)&p0;
                o.y = *(uint_t*)&p1;
                *(uint2*)&out[(size_t)(v0 + c) * G4 + 64 * w + 16 * mt + 4 * rg] = o;
            }
        }
    } else {
        const int v0 = (blockIdx.x - SYLL_V / 16) * 16;
        for (int i = tid; i < 16 * 32; i += 256) {
            int row = i >> 5, k = i & 31;
            Xh[row][k] = f2bf(word_emb[(size_t)v0 * 32 + i]);
        }
        __syncthreads();
#pragma unroll
        for (int dir = 0; dir < 2; dir++) {
            ushort_t* __restrict__ out = tab + (dir ? U16_PW_B : U16_PW_F);
#pragma unroll
            for (int mt = 0; mt < 4; mt++) {
                int base = (((dir * 4 + w) * 4 + mt) * 3 + 2) * 2;
                short8 Ah = wbuf[(size_t)(base + 0) * 64 + l];
                short8 Al = wbuf[(size_t)(base + 1) * 64 + l];
                f32x4 acc = *(const f32x4*)&biasbuf[dir * 256 + 64 * w + 16 * mt + 4 * rg];
                short8 Bf = *(const short8*)&Xh[c][rg * 8];
                acc = __builtin_amdgcn_mfma_f32_16x16x32_bf16(Ah, Bf, acc, 0, 0, 0);
                acc = __builtin_amdgcn_mfma_f32_16x16x32_bf16(Al, Bf, acc, 0, 0, 0);
                fp16x2 p0 = __builtin_amdgcn_cvt_pkrtz(acc[0], acc[1]);
                fp16x2 p1 = __builtin_amdgcn_cvt_pkrtz(acc[2], acc[3]);
                uint2 o;
                o.x = *(uint_t*)&p0;
                o.y = *(uint_t*)&p1;
                *(uint2*)&out[(size_t)(v0 + c) * G4 + 64 * w + 16 * mt + 4 * rg] = o;
            }
        }
    }
}

// ---------------------------------------------------------------------------
// Kernel 2: persistent BiLSTM via MFMA (round-10..17 verified, verbatim).
// ---------------------------------------------------------------------------
__global__ __launch_bounds__(256, 1) void lstm_kernel(
    const float* __restrict__ w_hh_f, const float* __restrict__ w_hh_b,
    const ushort_t* __restrict__ tab_u16, const int2* __restrict__ offs,
    ushort_t* __restrict__ h_out)
{
    const int dir = blockIdx.x & 1;
    const int bA = (blockIdx.x >> 1) * 4;
    const int tid = threadIdx.x;
    const int w = tid >> 6;
    const int l = tid & 63;
    const int rg = l >> 4;
    const int c = l & 15;
    const int cell = 16 * w + c;
    const int celloff = cell * 8;            // byte offset of this cell's 4 f16

    const char* __restrict__ tsb = (const char*)(tab_u16 + (dir ? U16_PS_B : U16_PS_F));
    const char* __restrict__ twb = (const char*)(tab_u16 + (dir ? U16_PW_B : U16_PW_F));
    const float* __restrict__ whh = dir ? w_hh_b : w_hh_f;

    // B-frags: B[k=chk*32+rg*8+j][n=cell] = sc*Whh[64*tau+cell][k]
    short8 bfrag[4][2];
#pragma unroll
    for (int tau = 0; tau < 4; tau++) {
        const float sc = (tau == 2) ? L2E2 : -L2E;
#pragma unroll
        for (int chk = 0; chk < 2; chk++)
            bfrag[tau][chk] = cvt8s(whh + (size_t)(64 * tau + cell) * Hd + chk * 32 + rg * 8, sc);
    }

    // h state: rows {0,4,8,12} hold chains 0..3; other rows stay zero.
    __shared__ __align__(16) ushort_t h_lds[2][16][72];
    for (int i = tid; i < 2 * 16 * 72; i += 256) ((ushort_t*)h_lds)[i] = 0;

    const int chain = bA + rg;
    const int p0 = dir ? (T_LEN - 1) : 0;
    const int2* __restrict__ op = offs + (size_t)(dir * B_SZ + chain) * TP;

    // 4-step-deep table pipeline; indices 8 steps ahead.
    fp16x4 tS[4], tW[4];
    int2 ix[4];
#pragma unroll
    for (int j = 0; j < 4; j++) {
        int2 o = op[j];
        tS[j] = *(const fp16x4*)(tsb + ((size_t)o.x + celloff));
        tW[j] = *(const fp16x4*)(twb + ((size_t)o.y + celloff));
        ix[j] = op[j + 4];
    }

    float cst = 0.f;
    ushort_t* hp = h_out + ((size_t)(chain * T_LEN + p0) * 2 + dir) * Hd + cell;
    const int hstep = dir ? -128 : 128;
    const f32x4 zro = {0.f, 0.f, 0.f, 0.f};
    __syncthreads();

    auto step = [&](auto STC, int t) {
        constexpr int ST = decltype(STC)::v;
        // consume psums loaded 4 steps ago; packed f16 add
        fp16x4 pp = tS[ST] + tW[ST];
        float ps0 = (float)pp[0];
        float ps1 = (float)pp[1];
        float ps2 = (float)pp[2];
        float ps3 = (float)pp[3];
        // issue table loads for t+4 (indices loaded 4 steps ago)
        tS[ST] = *(const fp16x4*)(tsb + ((size_t)ix[ST].x + celloff));
        tW[ST] = *(const fp16x4*)(twb + ((size_t)ix[ST].y + celloff));
        // index load for t+8 (sequential 8B, L2-resident)
        ix[ST] = op[t + 8];

        f32x4 cc0 = {ps0, 0.f, 0.f, 0.f};
        f32x4 cc1 = {ps1, 0.f, 0.f, 0.f};
        f32x4 cc2 = {ps2, 0.f, 0.f, 0.f};
        f32x4 cc3 = {ps3, 0.f, 0.f, 0.f};
        const ushort_t* hrow = &h_lds[t & 1][c][0];
        short8 a0 = *(const short8*)(hrow + rg * 8);
        short8 a1 = *(const short8*)(hrow + 32 + rg * 8);
        // 8 independent MFMAs; only element 0 of each pair-sum is consumed.
        f32x4 p00 = __builtin_amdgcn_mfma_f32_16x16x32_bf16(a0, bfrag[0][0], cc0, 0, 0, 0);
        f32x4 p10 = __builtin_amdgcn_mfma_f32_16x16x32_bf16(a0, bfrag[1][0], cc1, 0, 0, 0);
        f32x4 p20 = __builtin_amdgcn_mfma_f32_16x16x32_bf16(a0, bfrag[2][0], cc2, 0, 0, 0);
        f32x4 p30 = __builtin_amdgcn_mfma_f32_16x16x32_bf16(a0, bfrag[3][0], cc3, 0, 0, 0);
        f32x4 p01 = __builtin_amdgcn_mfma_f32_16x16x32_bf16(a1, bfrag[0][1], zro, 0, 0, 0);
        f32x4 p11 = __builtin_amdgcn_mfma_f32_16x16x32_bf16(a1, bfrag[1][1], zro, 0, 0, 0);
        f32x4 p21 = __builtin_amdgcn_mfma_f32_16x16x32_bf16(a1, bfrag[2][1], zro, 0, 0, 0);
        f32x4 p31 = __builtin_amdgcn_mfma_f32_16x16x32_bf16(a1, bfrag[3][1], zro, 0, 0, 0);

        // single cell-update: chain rg at cell (D row m = 4*rg -> element 0)
        float ai = p00[0] + p01[0];
        float af = p10[0] + p11[0];
        float ag = fminf(p20[0] + p21[0], 60.0f);
        float ao = p30[0] + p31[0];
        float ei = __builtin_amdgcn_exp2f(ai);
        float ef = __builtin_amdgcn_exp2f(af);
        float Eg = __builtin_amdgcn_exp2f(ag);
        float eo = __builtin_amdgcn_exp2f(ao);
        float e3 = 1.0f + ef;
        float pe = (1.0f + ei) * (1.0f + Eg);
        float num = __builtin_fmaf(Eg - 1.0f, e3, cst * pe);
        float cn = num * __builtin_amdgcn_rcpf(e3 * pe);
        cst = cn;
        float t2 = fminf(cn * L2E2, 60.0f);
        float E2 = __builtin_amdgcn_exp2f(t2);
        float h = (E2 - 1.0f) * __builtin_amdgcn_rcpf((1.0f + eo) * (1.0f + E2));

        ushort_t hb = f2bf(h);
        h_lds[(t + 1) & 1][4 * rg][cell] = hb;
        *hp = hb;
        hp += hstep;
        // LDS-only fence + raw barrier: vmcnt queue (table prefetch, h stores)
        // stays in flight across the barrier.
        __builtin_amdgcn_sched_barrier(0);
        asm volatile("s_waitcnt lgkmcnt(0)" ::: "memory");
        __builtin_amdgcn_s_barrier();
        __builtin_amdgcn_sched_barrier(0);
    };

    for (int t = 0; t < T_LEN; t += 4) {
        step(ic<0>{}, t);
        step(ic<1>{}, t + 1);
        step(ic<2>{}, t + 2);
        step(ic<3>{}, t + 3);
    }
}

// ---------------------------------------------------------------------------
// Kernel 3: FULLY FUSED emissions + CRF (round-17 verified, verbatim).
// ---------------------------------------------------------------------------
__global__ __launch_bounds__(256) void crf_all(
    const ushort_t* __restrict__ hseq, const float* __restrict__ W_tag,
    const float* __restrict__ b_tag, const float* __restrict__ trans,
    const int* __restrict__ tags, const float* __restrict__ start_t,
    const float* __restrict__ end_t, float* __restrict__ out)
{
    const int tid = threadIdx.x;
    const int w = tid >> 6;
    const int l = tid & 63;
    const int rg = l >> 4;
    const int n = l & 15;
    const int b = blockIdx.x;

    // region1: em_l (512*12 = 6144 floats) then bufA (64*120 = 7680 floats)
    __shared__ __align__(16) float region1[7680];
    __shared__ float bufB[3840];
    __shared__ float etT[120];
    __shared__ float e0_sh[10];
    __shared__ float num_sh[4];
    __shared__ float s_sh[2];
    __shared__ float sh_s;
    __shared__ float scl_sh[32];
    __shared__ float lg_sh[32];
    __shared__ float lg_acc_sh;

    float* em_l = region1;

    for (int i = tid; i < 120; i += 256) etT[i] = 0.f;
    __syncthreads();
    for (int i = tid; i < 100; i += 256) {
        int jj = i / 10, k = i % 10;
        etT[k * 12 + jj] = __expf(trans[i]);
    }

    // ---- phase A: emissions for hseq rows [b*512, +512) -> em_l ----
    short8 bf[4];
#pragma unroll
    for (int ch = 0; ch < 4; ch++) {
        if (n < KT) bf[ch] = cvt8(W_tag + (size_t)n * 128 + ch * 32 + rg * 8);
        else { short8 z = {0,0,0,0,0,0,0,0}; bf[ch] = z; }
    }
    const float btv = (n < KT) ? b_tag[n] : 0.f;
    const size_t gbase = (size_t)b * T_LEN;
#pragma unroll 4
    for (int gi = 0; gi < 8; gi++) {
        const int row0 = w * 128 + gi * 16;
        const ushort_t* __restrict__ ar = hseq + (gbase + row0 + n) * 128 + rg * 8;
        short8 a0 = *(const short8*)&ar[0];
        short8 a1 = *(const short8*)&ar[32];
        short8 a2 = *(const short8*)&ar[64];
        short8 a3 = *(const short8*)&ar[96];
        f32x4 acc = {btv, btv, btv, btv};
        acc = __builtin_amdgcn_mfma_f32_16x16x32_bf16(a0, bf[0], acc, 0, 0, 0);
        acc = __builtin_amdgcn_mfma_f32_16x16x32_bf16(a1, bf[1], acc, 0, 0, 0);
        acc = __builtin_amdgcn_mfma_f32_16x16x32_bf16(a2, bf[2], acc, 0, 0, 0);
        acc = __builtin_amdgcn_mfma_f32_16x16x32_bf16(a3, bf[3], acc, 0, 0, 0);
        if (n < KT) {
#pragma unroll
            for (int r = 0; r < 4; r++)
                em_l[(row0 + 4 * rg + r) * 12 + n] = acc[r];
        }
    }
    __syncthreads();

    // ---- phase B: chunk recursion, 2 threads/chunk x 5 rows ----
    float run[5][10];
    float s = 0.f;
    const int cch = tid >> 1;     // chunk 0..63 (tid < 128)
    const int half = tid & 1;     // rows half*5 .. half*5+4
    if (tid < 128) {
        const int t0 = (cch == 0) ? 1 : cch * 8;
        const int nt = (cch == 0) ? 7 : 8;
        float ecur[10];
#pragma unroll
        for (int k = 0; k < 10; k++) ecur[k] = em_l[t0 * 12 + k];
        {
            float mx = ecur[0];
#pragma unroll
            for (int k = 1; k < 10; k++) mx = fmaxf(mx, ecur[k]);
            s += mx;
            float ee[10];
#pragma unroll
            for (int k = 0; k < 10; k++) ee[k] = __expf(ecur[k] - mx);
#pragma unroll
            for (int r = 0; r < 5; r++)
#pragma unroll
                for (int k = 0; k < 10; k++)
                    run[r][k] = etT[k * 12 + (half * 5 + r)] * ee[k];
        }
        for (int li = 1; li < nt; li++) {
            float enx[10];
#pragma unroll
            for (int k = 0; k < 10; k++) enx[k] = em_l[(t0 + li) * 12 + k];
            float mx = enx[0];
#pragma unroll
            for (int k = 1; k < 10; k++) mx = fmaxf(mx, enx[k]);
            s += mx;
            float ee[10];
#pragma unroll
            for (int k = 0; k < 10; k++) ee[k] = __expf(enx[k] - mx);
#pragma unroll
            for (int r = 0; r < 5; r++) {
                float outp[10];
#pragma unroll
                for (int k = 0; k < 10; k++) {
                    float sum = 0.f;
#pragma unroll
                    for (int jj = 0; jj < 10; jj++) sum += run[r][jj] * etT[k * 12 + jj];
                    outp[k] = sum * ee[k];
                }
#pragma unroll
                for (int k = 0; k < 10; k++) run[r][k] = outp[k];
            }
        }
        float m = run[0][0];
#pragma unroll
        for (int r = 0; r < 5; r++)
#pragma unroll
            for (int k = 0; k < 10; k++) m = fmaxf(m, run[r][k]);
        m = fmaxf(m, __shfl_xor(m, 1));
        float inv = 1.0f / m;
        s += __logf(m);
#pragma unroll
        for (int r = 0; r < 5; r++)
#pragma unroll
            for (int k = 0; k < 10; k++) run[r][k] *= inv;
    }

    // ---- num / e0 / S1 partials (consume em_l before overwrite) ----
    {
        const int* __restrict__ tg = tags + b * T_LEN;
        float part = 0.f;
        for (int t = tid; t < T_LEN; t += 256) {
            int cur = tg[t];
            float ev = em_l[t * 12 + cur];
            if (t == 0) part += start_t[cur] + ev;
            else part += trans[tg[t - 1] * KT + cur] + ev;
            if (t == T_LEN - 1) part += end_t[cur];
        }
        for (int off = 32; off; off >>= 1) part += __shfl_down(part, off);
        if (l == 0) num_sh[w] = part;
    }
    if (tid < 10) e0_sh[tid] = em_l[tid];
    if (tid < 128) {
        float v = (half == 0) ? s : 0.f;
        for (int off = 32; off; off >>= 1) v += __shfl_down(v, off);
        if (l == 0) s_sh[w] = v;
    }
    if (tid == 0) lg_acc_sh = 0.f;
    __syncthreads();   // em_l consumers done; region1 may be overwritten

    // ---- phase C: verbatim crf_stage2 tree; bufA written from registers ----
    float* bufA = region1;
    if (tid == 0) sh_s = s_sh[0] + s_sh[1];
    if (tid < 128) {
#pragma unroll
        for (int r = 0; r < 5; r++)
#pragma unroll
            for (int k = 0; k < 10; k++)
                bufA[cch * 120 + (half * 5 + r) * 12 + k] = run[r][k];
    }
    __syncthreads();

    float* src = bufA;
    float* dst = bufB;
    for (int nn = 32; nn >= 1; nn >>= 1) {
        for (int idx = tid; idx < nn * 100; idx += 256) {
            int p = idx / 100, e = idx % 100, i = e / 10, k = e % 10;
            const float* A = src + (2 * p) * 120;
            const float* Bm = src + (2 * p + 1) * 120;
            float sum = 0.f;
#pragma unroll
            for (int jj = 0; jj < 10; jj++) sum += A[i * 12 + jj] * Bm[jj * 12 + k];
            dst[p * 120 + i * 12 + k] = sum;
        }
        __syncthreads();
        if (nn == 32 || nn == 8 || nn == 2) {
            if (tid < nn) {
                const float* M = dst + tid * 120;
                float mx = 0.f;
                for (int i = 0; i < 10; i++)
                    for (int k = 0; k < 10; k++) mx = fmaxf(mx, M[i * 12 + k]);
                scl_sh[tid] = 1.0f / mx;
                lg_sh[tid] = __logf(mx);
            }
            __syncthreads();
            if (tid == 0) {
                float ssum = 0.f;
                for (int p = 0; p < nn; p++) ssum += lg_sh[p];
                lg_acc_sh += ssum;
            }
            for (int idx = tid; idx < nn * 100; idx += 256) {
                int p = idx / 100, e = idx % 100;
                dst[p * 120 + (e / 10) * 12 + (e % 10)] *= scl_sh[p];
            }
            __syncthreads();
        }
        float* t_ = src; src = dst; dst = t_;
    }

    if (tid < 64) {
        float val = 0.f;
        float mx0 = 0.f;
        if (tid < 10) {
            mx0 = -1e30f;
            for (int jj = 0; jj < 10; jj++) mx0 = fmaxf(mx0, start_t[jj] + e0_sh[jj]);
            for (int jj = 0; jj < 10; jj++) {
                float v0 = __expf(start_t[jj] + e0_sh[jj] - mx0);
                val += v0 * src[jj * 12 + tid];
            }
            val *= __expf(end_t[tid]);
        }
        for (int off = 8; off; off >>= 1) val += __shfl_down(val, off);
        if (tid == 0) {
            float den = __logf(val) + mx0 + sh_s + lg_acc_sh;
            float numv = num_sh[0] + num_sh[1] + num_sh[2] + num_sh[3];
            float llh = numv - den;
            atomicAdd(out, llh * (-1.0f / 256.0f));
        }
    }
}

// ---------------------------------------------------------------------------
extern "C" void kernel_launch(void* const* d_in, const int* in_sizes, int n_in,
                              void* d_out, int out_size, void* d_ws, size_t ws_size,
                              hipStream_t stream) {
    const int* syll      = (const int*)d_in[0];
    const int* word      = (const int*)d_in[1];
    const int* tags      = (const int*)d_in[2];
    // d_in[3] = mask: all ones for this problem; unused.
    const float* syll_emb = (const float*)d_in[4];
    const float* word_emb = (const float*)d_in[5];
    const float* w_ih_f  = (const float*)d_in[6];
    const float* w_hh_f  = (const float*)d_in[7];
    const float* b_ih_f  = (const float*)d_in[8];
    const float* b_hh_f  = (const float*)d_in[9];
    const float* w_ih_b  = (const float*)d_in[10];
    const float* w_hh_b  = (const float*)d_in[11];
    const float* b_ih_b  = (const float*)d_in[12];
    const float* b_hh_b  = (const float*)d_in[13];
    const float* W_tag   = (const float*)d_in[14];
    const float* b_tag   = (const float*)d_in[15];
    const float* crf_start = (const float*)d_in[16];
    const float* crf_end   = (const float*)d_in[17];
    const float* crf_trans = (const float*)d_in[18];

    float* out = (float*)d_out;
    float* ws = (float*)d_ws;
    ushort_t* tab = (ushort_t*)ws;
    ushort_t* hseq = (ushort_t*)(ws + F_END);
    int2* offs = (int2*)(ws + F_OFFS);
    short8* wbuf = (short8*)(ws + F_WBUF);
    float* biasbuf = ws + F_BIAS;

    // merged wprep + offs + d_out zeroing (no hipMemsetAsync dispatch)
    prep_kernel<<<2 + B_SZ * 2, 256, 0, stream>>>(
        syll, word, offs,
        w_ih_f, w_ih_b, b_ih_f, b_hh_f, b_ih_b, b_hh_b, wbuf, biasbuf, out);

    // merged syll+word proj tables, both dirs per block
    proj_all<<<SYLL_V / 16 + WORD_V / 16, 256, 0, stream>>>(
        syll_emb, word_emb, wbuf, biasbuf, tab);

    // 128 blocks: block i handles chains 4*(i>>1)..4*(i>>1)+3, direction i&1
    lstm_kernel<<<B_SZ * 2 / 4, 256, 0, stream>>>(
        w_hh_f, w_hh_b, tab, offs, hseq);

    // fully fused emissions + CRF (1 batch per block, no global CRF arrays)
    crf_all<<<B_SZ, 256, 0, stream>>>(
        hseq, W_tag, b_tag, crf_trans, tags, crf_start, crf_end, out);
}